// Round 7
// baseline (137.371 us; speedup 1.0000x reference)
//
#include <hip/hip_runtime.h>
#include <hip/hip_bf16.h>

#define N_NODES 50000
#define N_EDGES 800000
#define D 128
#define SCAN_NB 49  // ceil(50000/1024)

static_assert(N_NODES < 65536, "src must fit in 16 bits for epack");

typedef __attribute__((ext_vector_type(8))) short short8;
typedef __attribute__((ext_vector_type(4))) float f32x4;
typedef unsigned int uint;
typedef unsigned short ushort;

__device__ __forceinline__ ushort f2bf(float f) {
    // float -> bf16 bits, round-to-nearest-even
    uint u = __float_as_uint(f);
    u += 0x7fffu + ((u >> 16) & 1u);
    return (ushort)(u >> 16);
}

// ---------------- prep: W fp32->bf16 AND zero deg (independent work) ----------------

__global__ __launch_bounds__(256) void sgcn_prep(
    const float* __restrict__ W, ushort* __restrict__ Wb, int* __restrict__ deg)
{
    int t = blockIdx.x * 256 + threadIdx.x;
    if (t < (D * D) / 4) {
        float4 a = reinterpret_cast<const float4*>(W)[t];
        ushort4 s;
        s.x = f2bf(a.x); s.y = f2bf(a.y); s.z = f2bf(a.z); s.w = f2bf(a.w);
        *reinterpret_cast<ushort4*>(Wb + (size_t)t * 4) = s;
    }
    if (t < N_NODES / 4) {  // 12500 int4 stores zero 50000 ints exactly
        reinterpret_cast<int4*>(deg)[t] = make_int4(0, 0, 0, 0);
    }
}

// ---------------- CSR build ----------------

__global__ __launch_bounds__(256) void sgcn_hist_rank(
    const int* __restrict__ dst, int* __restrict__ deg, int* __restrict__ rank)
{
    int e = blockIdx.x * 256 + threadIdx.x;
    if (e < N_EDGES)
        rank[e] = atomicAdd(&deg[dst[e]], 1);
}

__global__ __launch_bounds__(256) void sgcn_scan1(
    const int* __restrict__ deg, int* __restrict__ blockSum)
{
    __shared__ int red[256];
    int tid = threadIdx.x;
    int base = blockIdx.x * 1024 + tid * 4;
    int4 v = make_int4(0, 0, 0, 0);
    if (base < N_NODES) v = *reinterpret_cast<const int4*>(deg + base);
    red[tid] = v.x + v.y + v.z + v.w;
    __syncthreads();
    for (int off = 128; off > 0; off >>= 1) {
        if (tid < off) red[tid] += red[tid + off];
        __syncthreads();
    }
    if (tid == 0) blockSum[blockIdx.x] = red[0];
}

// Fused: per-block offset (reduce blockSum[0..blockIdx)) + local exclusive scan.
__global__ __launch_bounds__(256) void sgcn_scan3f(
    const int* __restrict__ deg, const int* __restrict__ blockSum,
    int* __restrict__ rowptr)
{
    __shared__ int part[256];
    __shared__ int off0;
    int tid = threadIdx.x;
    if (tid < 64) {
        int v = (tid < blockIdx.x) ? blockSum[tid] : 0;  // blockIdx.x <= 48
#pragma unroll
        for (int o = 32; o > 0; o >>= 1) v += __shfl_down(v, o);
        if (tid == 0) off0 = v;
    }
    int base = blockIdx.x * 1024 + tid * 4;
    int4 v = make_int4(0, 0, 0, 0);
    if (base < N_NODES) v = *reinterpret_cast<const int4*>(deg + base);
    int s = v.x + v.y + v.z + v.w;
    part[tid] = s;
    __syncthreads();
    for (int off = 1; off < 256; off <<= 1) {
        int mine  = part[tid];
        int other = (tid >= off) ? part[tid - off] : 0;
        __syncthreads();
        part[tid] = mine + other;
        __syncthreads();
    }
    int run = off0 + ((tid == 0) ? 0 : part[tid - 1]);
    if (base < N_NODES) {
        int4 r;
        r.x = run;
        r.y = run + v.x;
        r.z = r.y + v.y;
        r.w = r.z + v.z;
        *reinterpret_cast<int4*>(rowptr + base) = r;
        if (base + 4 == N_NODES) rowptr[N_NODES] = r.w + v.w;
    }
}

// epack[pos] = (bf16(val) << 16) | src  — 4 bytes per edge.
__global__ __launch_bounds__(256) void sgcn_permute(
    const int* __restrict__ src, const int* __restrict__ dst,
    const float* __restrict__ val, const int* __restrict__ rowptr,
    const int* __restrict__ rank, uint* __restrict__ epack)
{
    int e = blockIdx.x * 256 + threadIdx.x;
    if (e < N_EDGES) {
        int pos = rowptr[dst[e]] + rank[e];
        epack[pos] = ((uint)f2bf(val[e]) << 16) | (uint)src[e];
    }
}

// ---------------- MFMA GEMM first: y = x @ W^T (bf16 out) ----------------
// Wave: 16-row x 128-col stripe. A: lane holds x[m0+(l&15)][kb*8+j] (fp32 read,
// bf16 convert inline). B: lane holds W[nt*16+(l&15)][kb*8+j] (row-major Wb).
// C/D: col = l&15 (n), row = kb*4 + r (m). [m89 layout]

__global__ __launch_bounds__(256) void sgcn_gemm_y(
    const float* __restrict__ x, const ushort* __restrict__ Wb,
    ushort* __restrict__ y)
{
    int wave = threadIdx.x >> 6;
    int lane = threadIdx.x & 63;
    int lm = lane & 15;
    int kb = lane >> 4;

    short8 bfr[8][4];
#pragma unroll
    for (int nt = 0; nt < 8; ++nt)
#pragma unroll
        for (int kk = 0; kk < 4; ++kk)
            bfr[nt][kk] = *reinterpret_cast<const short8*>(
                Wb + (nt * 16 + lm) * D + kk * 32 + kb * 8);

    const int nMT = N_NODES / 16;  // 3125
    int mt0 = blockIdx.x * 4 + wave;
    int strideMT = gridDim.x * 4;
    for (int mt = mt0; mt < nMT; mt += strideMT) {
        int m0 = mt * 16;
        const float* xrow = x + (long)(m0 + lm) * D + kb * 8;
        short8 afr[4];
#pragma unroll
        for (int kk = 0; kk < 4; ++kk) {
            float4 a = *reinterpret_cast<const float4*>(xrow + kk * 32);
            float4 c = *reinterpret_cast<const float4*>(xrow + kk * 32 + 4);
            short8 s;
            s[0] = (short)f2bf(a.x); s[1] = (short)f2bf(a.y);
            s[2] = (short)f2bf(a.z); s[3] = (short)f2bf(a.w);
            s[4] = (short)f2bf(c.x); s[5] = (short)f2bf(c.y);
            s[6] = (short)f2bf(c.z); s[7] = (short)f2bf(c.w);
            afr[kk] = s;
        }
#pragma unroll
        for (int nt = 0; nt < 8; ++nt) {
            f32x4 acc = {0.f, 0.f, 0.f, 0.f};
#pragma unroll
            for (int kk = 0; kk < 4; ++kk)
                acc = __builtin_amdgcn_mfma_f32_16x16x32_bf16(afr[kk], bfr[nt][kk], acc, 0, 0, 0);
            ushort* yp = y + (long)(m0 + kb * 4) * D + nt * 16 + lm;
#pragma unroll
            for (int r = 0; r < 4; ++r)
                yp[(long)r * D] = f2bf(acc[r]);
        }
    }
}

// ---------------- Aggregation over y, channel-split, fused bias+relu ----------------
// yb is [N][64] uints (packed bf16 pairs). Pass handles channels
// [PASS*64, PASS*64+64) = 32 uints/row. Half-wave per edge: 2 edges/iter.

__device__ __forceinline__ float bflo(uint u) { return __uint_as_float(u << 16); }
__device__ __forceinline__ float bfhi(uint u) { return __uint_as_float(u & 0xffff0000u); }

template<int PASS>
__global__ __launch_bounds__(256) void sgcn_aggregate(
    const uint* __restrict__ yb, const int* __restrict__ rowptr,
    const uint* __restrict__ ep, const float* __restrict__ bias,
    float* __restrict__ out)
{
    int gw   = (blockIdx.x * 256 + threadIdx.x) >> 6;
    int lane = threadIdx.x & 63;
    int h    = lane >> 5;        // which edge of the pair
    int l    = lane & 31;        // uint index within the 64-ch half
    int nW   = (gridDim.x * 256) >> 6;
    float2 bv = *reinterpret_cast<const float2*>(bias + PASS * 64 + 2 * l);
    for (int n = gw; n < N_NODES; n += nW) {
        int j0 = rowptr[n], j1 = rowptr[n + 1];
        float ax = 0.f, ay = 0.f;
        int j = j0;
        for (; j + 4 <= j1; j += 4) {  // 4 edges: {j..j+3}, halves take h and 2+h
            uint p0 = ep[j + h];
            uint p1 = ep[j + 2 + h];
            uint u0 = yb[(long)(p0 & 0xffffu) * 64 + PASS * 32 + l];
            uint u1 = yb[(long)(p1 & 0xffffu) * 64 + PASS * 32 + l];
            float v0 = __uint_as_float(p0 & 0xffff0000u);
            float v1 = __uint_as_float(p1 & 0xffff0000u);
            ax += v0 * bflo(u0) + v1 * bflo(u1);
            ay += v0 * bfhi(u0) + v1 * bfhi(u1);
        }
        for (; j < j1; j += 2) {  // tail: up to 3 edges, guarded
            int jj = j + h;
            if (jj < j1) {
                uint p = ep[jj];
                uint u = yb[(long)(p & 0xffffu) * 64 + PASS * 32 + l];
                float v = __uint_as_float(p & 0xffff0000u);
                ax += v * bflo(u);
                ay += v * bfhi(u);
            }
        }
        ax += __shfl_xor(ax, 32);
        ay += __shfl_xor(ay, 32);
        if (h == 0) {
            float2 r;
            r.x = fmaxf(ax + bv.x, 0.f);
            r.y = fmaxf(ay + bv.y, 0.f);
            *reinterpret_cast<float2*>(out + (long)n * D + PASS * 64 + 2 * l) = r;
        }
    }
}

extern "C" void kernel_launch(void* const* d_in, const int* in_sizes, int n_in,
                              void* d_out, int out_size, void* d_ws, size_t ws_size,
                              hipStream_t stream) {
    const float* x   = (const float*)d_in[0];
    const int*   es  = (const int*)d_in[1];
    const int*   ed  = (const int*)d_in[2];
    const float* ev  = (const float*)d_in[3];
    const float* W   = (const float*)d_in[4];
    const float* b   = (const float*)d_in[5];
    float* out = (float*)d_out;

    // Workspace layout (16B-aligned fields), total ~16.3 MB
    char* ws = (char*)d_ws;
    size_t off = 0;
    uint*   yb       = (uint*)  (ws + off); off += (size_t)N_NODES * (D / 2) * sizeof(uint);   // 12.8 MB
    ushort* Wb       = (ushort*)(ws + off); off += (size_t)D * D * sizeof(ushort);             // 32 KB
    uint*   epack    = (uint*)  (ws + off); off += (size_t)N_EDGES * sizeof(uint);             // 3.2 MB
    int*    rowptr   = (int*)   (ws + off); off += ((size_t)(N_NODES + 1) * sizeof(int) + 15) & ~15ull;
    int*    deg      = (int*)   (ws + off); off += (size_t)N_NODES * sizeof(int);
    int*    blockSum = (int*)   (ws + off); off += 64 * sizeof(int);
    // rank overlays d_out: rank is dead before the aggregates (sole writers of out).
    int* rank = (int*)d_out;

    const int EB = (N_EDGES + 255) / 256;  // 3125

    sgcn_prep<<<64, 256, 0, stream>>>(W, Wb, deg);
    sgcn_gemm_y<<<512, 256, 0, stream>>>(x, Wb, (ushort*)yb);
    sgcn_hist_rank<<<EB, 256, 0, stream>>>(ed, deg, rank);
    sgcn_scan1<<<SCAN_NB, 256, 0, stream>>>(deg, blockSum);
    sgcn_scan3f<<<SCAN_NB, 256, 0, stream>>>(deg, blockSum, rowptr);
    sgcn_permute<<<EB, 256, 0, stream>>>(es, ed, ev, rowptr, rank, epack);
    sgcn_aggregate<0><<<2048, 256, 0, stream>>>(yb, rowptr, epack, b, out);
    sgcn_aggregate<1><<<2048, 256, 0, stream>>>(yb, rowptr, epack, b, out);
}

// Round 9
// 116.221 us; speedup vs baseline: 1.1820x; 1.1820x over previous
//
#include <hip/hip_runtime.h>
#include <hip/hip_bf16.h>

#define N_NODES 50000
#define N_EDGES 800000
#define D 128
#define SCAN_NB 49  // ceil(50000/1024)

static_assert(N_NODES < 65536, "src must fit in 16 bits for epack");

typedef __attribute__((ext_vector_type(8))) short short8;
typedef __attribute__((ext_vector_type(4))) float f32x4;
typedef unsigned int uint;
typedef unsigned short ushort;

__device__ __forceinline__ ushort f2bf(float f) {
    // float -> bf16 bits, round-to-nearest-even
    uint u = __float_as_uint(f);
    u += 0x7fffu + ((u >> 16) & 1u);
    return (ushort)(u >> 16);
}

__device__ __forceinline__ float bflo(uint u) { return __uint_as_float(u << 16); }
__device__ __forceinline__ float bfhi(uint u) { return __uint_as_float(u & 0xffff0000u); }

// ---------------- prep: W fp32->bf16 AND zero deg (independent work) ----------------

__global__ __launch_bounds__(256) void sgcn_prep(
    const float* __restrict__ W, ushort* __restrict__ Wb, int* __restrict__ deg)
{
    int t = blockIdx.x * 256 + threadIdx.x;
    if (t < (D * D) / 4) {
        float4 a = reinterpret_cast<const float4*>(W)[t];
        ushort4 s;
        s.x = f2bf(a.x); s.y = f2bf(a.y); s.z = f2bf(a.z); s.w = f2bf(a.w);
        *reinterpret_cast<ushort4*>(Wb + (size_t)t * 4) = s;
    }
    if (t < N_NODES / 4) {  // 12500 int4 stores zero 50000 ints exactly
        reinterpret_cast<int4*>(deg)[t] = make_int4(0, 0, 0, 0);
    }
}

// ---------------- CSR build ----------------

__global__ __launch_bounds__(256) void sgcn_hist_rank(
    const int* __restrict__ dst, int* __restrict__ deg, int* __restrict__ rank)
{
    int e = blockIdx.x * 256 + threadIdx.x;
    if (e < N_EDGES)
        rank[e] = atomicAdd(&deg[dst[e]], 1);
}

// Fused scan: block b computes off0 = sum(deg[0 .. b*1024)) itself (deg is L2-hot),
// then exclusive-scans its own 1024-chunk. One dispatch, no blockSum roundtrip.
__global__ __launch_bounds__(256) void sgcn_scanf(
    const int* __restrict__ deg, int* __restrict__ rowptr)
{
    __shared__ int part[256];
    __shared__ int soff;
    int tid = threadIdx.x;
    int b = blockIdx.x;

    const int4* d4 = reinterpret_cast<const int4*>(deg);
    int pre = 0;
    for (int i = tid; i < b * 256; i += 256) {
        int4 v = d4[i];
        pre += v.x + v.y + v.z + v.w;
    }
    part[tid] = pre;
    __syncthreads();
    for (int off = 128; off > 0; off >>= 1) {
        if (tid < off) part[tid] += part[tid + off];
        __syncthreads();
    }
    if (tid == 0) soff = part[0];
    __syncthreads();

    int base = b * 1024 + tid * 4;
    int4 v = make_int4(0, 0, 0, 0);
    if (base < N_NODES) v = *reinterpret_cast<const int4*>(deg + base);
    int s = v.x + v.y + v.z + v.w;
    part[tid] = s;
    __syncthreads();
    for (int off = 1; off < 256; off <<= 1) {
        int mine  = part[tid];
        int other = (tid >= off) ? part[tid - off] : 0;
        __syncthreads();
        part[tid] = mine + other;
        __syncthreads();
    }
    int run = soff + ((tid == 0) ? 0 : part[tid - 1]);
    if (base < N_NODES) {
        int4 r;
        r.x = run;
        r.y = run + v.x;
        r.z = r.y + v.y;
        r.w = r.z + v.z;
        *reinterpret_cast<int4*>(rowptr + base) = r;
        if (base + 4 == N_NODES) rowptr[N_NODES] = r.w + v.w;
    }
}

// epack[pos] = (bf16(val) << 16) | src  — 4 bytes per edge.
__global__ __launch_bounds__(256) void sgcn_permute(
    const int* __restrict__ src, const int* __restrict__ dst,
    const float* __restrict__ val, const int* __restrict__ rowptr,
    const int* __restrict__ rank, uint* __restrict__ epack)
{
    int e = blockIdx.x * 256 + threadIdx.x;
    if (e < N_EDGES) {
        int pos = rowptr[dst[e]] + rank[e];
        epack[pos] = ((uint)f2bf(val[e]) << 16) | (uint)src[e];
    }
}

// ---------------- MFMA GEMM first: y = x @ W^T (bf16 out) ----------------
// Wave: 16-row x 128-col stripe. A: lane holds x[m0+(l&15)][kb*8+j] (fp32 read,
// bf16 convert inline). B: lane holds W[nt*16+(l&15)][kb*8+j] (row-major Wb).
// C/D: col = l&15 (n), row = kb*4 + r (m). [m89 layout]

__global__ __launch_bounds__(256) void sgcn_gemm_y(
    const float* __restrict__ x, const ushort* __restrict__ Wb,
    ushort* __restrict__ y)
{
    int wave = threadIdx.x >> 6;
    int lane = threadIdx.x & 63;
    int lm = lane & 15;
    int kb = lane >> 4;

    short8 bfr[8][4];
#pragma unroll
    for (int nt = 0; nt < 8; ++nt)
#pragma unroll
        for (int kk = 0; kk < 4; ++kk)
            bfr[nt][kk] = *reinterpret_cast<const short8*>(
                Wb + (nt * 16 + lm) * D + kk * 32 + kb * 8);

    const int nMT = N_NODES / 16;  // 3125
    int mt0 = blockIdx.x * 4 + wave;
    int strideMT = gridDim.x * 4;
    for (int mt = mt0; mt < nMT; mt += strideMT) {
        int m0 = mt * 16;
        const float* xrow = x + (long)(m0 + lm) * D + kb * 8;
        short8 afr[4];
#pragma unroll
        for (int kk = 0; kk < 4; ++kk) {
            float4 a = *reinterpret_cast<const float4*>(xrow + kk * 32);
            float4 c = *reinterpret_cast<const float4*>(xrow + kk * 32 + 4);
            short8 s;
            s[0] = (short)f2bf(a.x); s[1] = (short)f2bf(a.y);
            s[2] = (short)f2bf(a.z); s[3] = (short)f2bf(a.w);
            s[4] = (short)f2bf(c.x); s[5] = (short)f2bf(c.y);
            s[6] = (short)f2bf(c.z); s[7] = (short)f2bf(c.w);
            afr[kk] = s;
        }
#pragma unroll
        for (int nt = 0; nt < 8; ++nt) {
            f32x4 acc = {0.f, 0.f, 0.f, 0.f};
#pragma unroll
            for (int kk = 0; kk < 4; ++kk)
                acc = __builtin_amdgcn_mfma_f32_16x16x32_bf16(afr[kk], bfr[nt][kk], acc, 0, 0, 0);
            ushort* yp = y + (long)(m0 + kb * 4) * D + nt * 16 + lm;
#pragma unroll
            for (int r = 0; r < 4; ++r)
                yp[(long)r * D] = f2bf(acc[r]);
        }
    }
}

// ---------------- Aggregation: quarter-wave per edge, single pass ----------------
// yb rows = 64 uints (256 B). Lane l: edge slot q=l>>4, channel group c=l&15
// (channels c*8 .. c*8+7 via uint4). 4 edges per load instruction; 8-edge unroll.
// Cross-quarter reduce via shfl_xor(16,32); quarter 0 stores nontemporal (out is
// never re-read — don't evict yb from L2).

__global__ __launch_bounds__(256) void sgcn_aggregate(
    const uint* __restrict__ yb, const int* __restrict__ rowptr,
    const uint* __restrict__ ep, const float* __restrict__ bias,
    float* __restrict__ out)
{
    int gw   = (blockIdx.x * 256 + threadIdx.x) >> 6;
    int lane = threadIdx.x & 63;
    int q    = lane >> 4;
    int c    = lane & 15;
    int nW   = (gridDim.x * 256) >> 6;
    float4 bv0 = *reinterpret_cast<const float4*>(bias + c * 8);
    float4 bv1 = *reinterpret_cast<const float4*>(bias + c * 8 + 4);

    for (int n = gw; n < N_NODES; n += nW) {
        int j0 = rowptr[n], j1 = rowptr[n + 1];
        float a0 = 0.f, a1 = 0.f, a2 = 0.f, a3 = 0.f;
        float a4 = 0.f, a5 = 0.f, a6 = 0.f, a7 = 0.f;
        int j = j0;
        for (; j + 8 <= j1; j += 8) {
            uint p0 = ep[j + q];
            uint p1 = ep[j + 4 + q];
            uint4 u0 = *reinterpret_cast<const uint4*>(yb + (size_t)(p0 & 0xffffu) * 64 + c * 4);
            uint4 u1 = *reinterpret_cast<const uint4*>(yb + (size_t)(p1 & 0xffffu) * 64 + c * 4);
            float v0 = __uint_as_float(p0 & 0xffff0000u);
            float v1 = __uint_as_float(p1 & 0xffff0000u);
            a0 += v0 * bflo(u0.x) + v1 * bflo(u1.x);
            a1 += v0 * bfhi(u0.x) + v1 * bfhi(u1.x);
            a2 += v0 * bflo(u0.y) + v1 * bflo(u1.y);
            a3 += v0 * bfhi(u0.y) + v1 * bfhi(u1.y);
            a4 += v0 * bflo(u0.z) + v1 * bflo(u1.z);
            a5 += v0 * bfhi(u0.z) + v1 * bfhi(u1.z);
            a6 += v0 * bflo(u0.w) + v1 * bflo(u1.w);
            a7 += v0 * bfhi(u0.w) + v1 * bfhi(u1.w);
        }
        for (; j < j1; j += 4) {
            int jj = j + q;
            if (jj < j1) {
                uint p = ep[jj];
                uint4 u = *reinterpret_cast<const uint4*>(yb + (size_t)(p & 0xffffu) * 64 + c * 4);
                float v = __uint_as_float(p & 0xffff0000u);
                a0 += v * bflo(u.x); a1 += v * bfhi(u.x);
                a2 += v * bflo(u.y); a3 += v * bfhi(u.y);
                a4 += v * bflo(u.z); a5 += v * bfhi(u.z);
                a6 += v * bflo(u.w); a7 += v * bfhi(u.w);
            }
        }
        a0 += __shfl_xor(a0, 16); a0 += __shfl_xor(a0, 32);
        a1 += __shfl_xor(a1, 16); a1 += __shfl_xor(a1, 32);
        a2 += __shfl_xor(a2, 16); a2 += __shfl_xor(a2, 32);
        a3 += __shfl_xor(a3, 16); a3 += __shfl_xor(a3, 32);
        a4 += __shfl_xor(a4, 16); a4 += __shfl_xor(a4, 32);
        a5 += __shfl_xor(a5, 16); a5 += __shfl_xor(a5, 32);
        a6 += __shfl_xor(a6, 16); a6 += __shfl_xor(a6, 32);
        a7 += __shfl_xor(a7, 16); a7 += __shfl_xor(a7, 32);
        if (q == 0) {
            f32x4 r0, r1;
            r0[0] = fmaxf(a0 + bv0.x, 0.f);
            r0[1] = fmaxf(a1 + bv0.y, 0.f);
            r0[2] = fmaxf(a2 + bv0.z, 0.f);
            r0[3] = fmaxf(a3 + bv0.w, 0.f);
            r1[0] = fmaxf(a4 + bv1.x, 0.f);
            r1[1] = fmaxf(a5 + bv1.y, 0.f);
            r1[2] = fmaxf(a6 + bv1.z, 0.f);
            r1[3] = fmaxf(a7 + bv1.w, 0.f);
            f32x4* op = reinterpret_cast<f32x4*>(out + (long)n * D + c * 8);
            __builtin_nontemporal_store(r0, op);
            __builtin_nontemporal_store(r1, op + 1);
        }
    }
}

extern "C" void kernel_launch(void* const* d_in, const int* in_sizes, int n_in,
                              void* d_out, int out_size, void* d_ws, size_t ws_size,
                              hipStream_t stream) {
    const float* x   = (const float*)d_in[0];
    const int*   es  = (const int*)d_in[1];
    const int*   ed  = (const int*)d_in[2];
    const float* ev  = (const float*)d_in[3];
    const float* W   = (const float*)d_in[4];
    const float* b   = (const float*)d_in[5];
    float* out = (float*)d_out;

    // Workspace layout (16B-aligned fields), total ~16.3 MB
    char* ws = (char*)d_ws;
    size_t off = 0;
    uint*   yb       = (uint*)  (ws + off); off += (size_t)N_NODES * (D / 2) * sizeof(uint);   // 12.8 MB
    ushort* Wb       = (ushort*)(ws + off); off += (size_t)D * D * sizeof(ushort);             // 32 KB
    uint*   epack    = (uint*)  (ws + off); off += (size_t)N_EDGES * sizeof(uint);             // 3.2 MB
    int*    rowptr   = (int*)   (ws + off); off += ((size_t)(N_NODES + 1) * sizeof(int) + 15) & ~15ull;
    int*    deg      = (int*)   (ws + off); off += (size_t)N_NODES * sizeof(int);
    // rank overlays d_out: rank is dead before sgcn_aggregate (sole writer of out).
    int* rank = (int*)d_out;

    const int EB = (N_EDGES + 255) / 256;  // 3125

    sgcn_prep<<<64, 256, 0, stream>>>(W, Wb, deg);
    sgcn_gemm_y<<<512, 256, 0, stream>>>(x, Wb, (ushort*)yb);
    sgcn_hist_rank<<<EB, 256, 0, stream>>>(ed, deg, rank);
    sgcn_scanf<<<SCAN_NB, 256, 0, stream>>>(deg, rowptr);
    sgcn_permute<<<EB, 256, 0, stream>>>(es, ed, ev, rowptr, rank, epack);
    sgcn_aggregate<<<2048, 256, 0, stream>>>(yb, rowptr, epack, b, out);
}